// Round 8
// baseline (344.131 us; speedup 1.0000x reference)
//
#include <hip/hip_runtime.h>
#include <hip/hip_bf16.h>

// Problem constants
#define NB 16
#define ND 512
#define NT 2048
#define TM1 2047
#define NHD 256

typedef __attribute__((ext_vector_type(8))) short bf16x8;
typedef __attribute__((ext_vector_type(4))) float f32x4;
typedef unsigned short ushort_t;
typedef unsigned int uint_t;

// ws layout (float offsets): zeroed head [0,49152), wsum, wkqT, chunk bufs.
#define G0_OFF    0ull
#define G0_ELEMS  (16ull * 2047ull)        // 32,752
#define R0_OFF    32768ull                 // r0acc [16][512]
#define SX_OFF    40960ull                 // sxacc [16][512]
#define ZERO_FLOATS 49152ull               // zeroed by k_prep
#define WSUM_OFF  49152ull
#define WKQT_OFF  49408ull                 // 512*512 bf16 = 131072 floats
#define CHUNK_OFF 180480ull
#define BATCH_US  (2048ull * 512ull)       // ushorts per batch per array (2 MB)
#define BATCH_FLOATS (2ull * 524288ull)    // qdb + xst floats per batch (4 MB)

__device__ __forceinline__ ushort_t f2bf(float x) {
    union { float f; uint_t u; } v; v.f = x;
    uint_t r = v.u + 0x7FFFu + ((v.u >> 16) & 1u);  // round-to-nearest-even
    return (ushort_t)(r >> 16);
}
__device__ __forceinline__ float bf2f(uint_t u) {
    union { uint_t u; float f; } v; v.u = u << 16;
    return v.f;
}

// Async global->LDS DMA, 16 B/lane, 1024 B/wave-instruction.
__device__ __forceinline__ void async_copy16(const ushort_t* g, ushort_t* l) {
    __builtin_amdgcn_global_load_lds(
        (const __attribute__((address_space(1))) void*)g,
        (__attribute__((address_space(3))) void*)l, 16, 0, 0);
}

// --- prep: wkqT = bf16(wkq^T);  zero g0/r0acc/sxacc;  wsum = sum(wlast) --
__global__ __launch_bounds__(256) void k_prep(const float* __restrict__ wkq,
                                              ushort_t* __restrict__ wkqT,
                                              const float* __restrict__ wlast,
                                              float* __restrict__ wsum,
                                              float* __restrict__ zbase) {
    __shared__ float tile[32][33];
    const int j0 = blockIdx.x * 32, d0 = blockIdx.y * 32;
    const int c = threadIdx.x & 31, r = threadIdx.x >> 5;  // r in 0..7
    #pragma unroll
    for (int i = 0; i < 4; ++i) {
        const int d = r + i * 8;
        tile[d][c] = wkq[(size_t)(d0 + d) * ND + j0 + c];
    }
    __syncthreads();
    #pragma unroll
    for (int i = 0; i < 4; ++i) {
        const int j = r + i * 8;
        wkqT[(size_t)(j0 + j) * ND + d0 + c] = f2bf(tile[c][j]);
    }
    // zero head scratch: 49152 floats over 256 blocks x 192 threads
    const int bid = blockIdx.y * 16 + blockIdx.x;
    if (threadIdx.x < 192) zbase[bid * 192 + threadIdx.x] = 0.f;
    // block 0 reduces wlast -> wsum
    if (bid == 0) {
        __shared__ float red[256];
        float s = 0.f;
        for (int t = threadIdx.x; t < NT; t += 256) s += wlast[t];
        red[threadIdx.x] = s;
        __syncthreads();
        for (int off = 128; off > 0; off >>= 1) {
            if (threadIdx.x < off) red[threadIdx.x] += red[threadIdx.x + off];
            __syncthreads();
        }
        if (threadIdx.x == 0) *wsum = red[0];
    }
}

// --- xst[c][t][d] = bf16(xs[b0+c][d][t]); 64x64 tiles, vectorized IO -----
__global__ __launch_bounds__(256) void k_cvt_xst(const float* __restrict__ xs,
                                                 ushort_t* __restrict__ xst, int b0) {
    __shared__ float tile[64][65];
    const int t0 = blockIdx.x * 64, d0 = blockIdx.y * 64;
    const int cc = blockIdx.z;
    const float* xb = xs + (size_t)(b0 + cc) * ND * NT;
    ushort_t* xo = xst + (size_t)cc * BATCH_US;
    const int r = threadIdx.x >> 4;          // 0..15
    const int c4 = (threadIdx.x & 15) * 4;   // 0..60
    #pragma unroll
    for (int i = 0; i < 4; ++i) {
        const int d = r + i * 16;
        *(float4*)&tile[d][c4] = *(const float4*)&xb[(size_t)(d0 + d) * NT + t0 + c4];
    }
    __syncthreads();
    #pragma unroll
    for (int i = 0; i < 4; ++i) {
        const int t = r + i * 16;
        const uint_t p0 = (uint_t)f2bf(tile[c4 + 0][t]) | ((uint_t)f2bf(tile[c4 + 1][t]) << 16);
        const uint_t p1 = (uint_t)f2bf(tile[c4 + 2][t]) | ((uint_t)f2bf(tile[c4 + 3][t]) << 16);
        uint2 pk; pk.x = p0; pk.y = p1;
        *(uint2*)&xo[(size_t)(t0 + t) * ND + d0 + c4] = pk;
    }
}

// --- qdb[c][s][j] = bf16( sign_j * sum_d xst[c][s][d] * wkqT[j][d] ) -----
__global__ __launch_bounds__(256) void k_qd(const ushort_t* __restrict__ xst,
                                            const ushort_t* __restrict__ wkqT,
                                            ushort_t* __restrict__ qdb) {
    const int j0 = blockIdx.x * 128;
    const int s0 = blockIdx.y * 128;
    const int cc = blockIdx.z;
    __shared__ __align__(16) ushort_t As[128 * 64];
    __shared__ __align__(16) ushort_t Bs[128 * 64];
    const int tid = threadIdx.x;
    const int wave = tid >> 6, lane = tid & 63;
    const int l15 = lane & 15, quad = lane >> 4;
    const int wm = wave >> 1, wn = wave & 1;
    const int swz = l15 & 7;
    const int lrow = lane >> 3;
    const size_t lsrc = (size_t)lrow * ND + (size_t)(((lane & 7) ^ lrow) << 3);
    const ushort_t* xa = xst + (size_t)cc * BATCH_US + (size_t)s0 * ND;
    const ushort_t* wb = wkqT + (size_t)j0 * ND;
    ushort_t* qo = qdb + (size_t)cc * BATCH_US;
    f32x4 acc[4][4];
    #pragma unroll
    for (int mi = 0; mi < 4; ++mi)
        #pragma unroll
        for (int nj = 0; nj < 4; ++nj) acc[mi][nj] = (f32x4){0.f, 0.f, 0.f, 0.f};
    for (int ks = 0; ks < 8; ++ks) {
        const int k0 = ks * 64;
        #pragma unroll
        for (int n = 0; n < 4; ++n) {
            const int rbase = wave * 32 + n * 8;
            async_copy16(xa + (size_t)rbase * ND + k0 + lsrc, &As[rbase * 64]);
            async_copy16(wb + (size_t)rbase * ND + k0 + lsrc, &Bs[rbase * 64]);
        }
        __builtin_amdgcn_s_waitcnt(0);
        __syncthreads();
        #pragma unroll
        for (int kc = 0; kc < 2; ++kc) {
            bf16x8 af[4], bfr[4];
            #pragma unroll
            for (int mi = 0; mi < 4; ++mi)
                af[mi] = *(const bf16x8*)&As[(wm * 64 + mi * 16 + l15) * 64 + (((kc * 4 + quad) ^ swz) << 3)];
            #pragma unroll
            for (int nj = 0; nj < 4; ++nj)
                bfr[nj] = *(const bf16x8*)&Bs[(wn * 64 + nj * 16 + l15) * 64 + (((kc * 4 + quad) ^ swz) << 3)];
            #pragma unroll
            for (int mi = 0; mi < 4; ++mi)
                #pragma unroll
                for (int nj = 0; nj < 4; ++nj)
                    acc[mi][nj] = __builtin_amdgcn_mfma_f32_16x16x32_bf16(af[mi], bfr[nj], acc[mi][nj], 0, 0, 0);
        }
        __syncthreads();
    }
    #pragma unroll
    for (int mi = 0; mi < 4; ++mi) {
        const int srow = s0 + wm * 64 + mi * 16 + quad * 4;
        #pragma unroll
        for (int nj = 0; nj < 4; ++nj) {
            const int jcol = j0 + wn * 64 + nj * 16 + l15;
            const float sgn = (jcol < NHD) ? 1.f : -1.f;
            #pragma unroll
            for (int r = 0; r < 4; ++r)
                qo[(size_t)(srow + r) * ND + jcol] = f2bf(sgn * acc[mi][nj][r]);
        }
    }
}

// --- g0[b,s] += sum_t sigmoid(Delta[b,s,t]) * w[t] -----------------------
__global__ __launch_bounds__(256) void k_attn(const ushort_t* __restrict__ qdb,
                                              const ushort_t* __restrict__ xst,
                                              const float* __restrict__ wlast,
                                              float* __restrict__ g0, int b0) {
    const int t0 = blockIdx.x * 128;
    const int s0 = blockIdx.y * 128;
    const int cc = blockIdx.z;
    const int b = b0 + cc;
    __shared__ __align__(16) ushort_t As[128 * 64];
    __shared__ __align__(16) ushort_t Bs[128 * 64];
    const int tid = threadIdx.x;
    const int wave = tid >> 6, lane = tid & 63;
    const int l15 = lane & 15, quad = lane >> 4;
    const int wm = wave >> 1, wn = wave & 1;
    const int swz = l15 & 7;
    const int lrow = lane >> 3;
    const size_t lsrc = (size_t)lrow * ND + (size_t)(((lane & 7) ^ lrow) << 3);
    const ushort_t* qa = qdb + (size_t)cc * BATCH_US + (size_t)s0 * ND;
    const ushort_t* xa = xst + (size_t)cc * BATCH_US + (size_t)t0 * ND;
    f32x4 acc[4][4];
    #pragma unroll
    for (int mi = 0; mi < 4; ++mi)
        #pragma unroll
        for (int nj = 0; nj < 4; ++nj) acc[mi][nj] = (f32x4){0.f, 0.f, 0.f, 0.f};
    for (int ks = 0; ks < 8; ++ks) {
        const int k0 = ks * 64;
        #pragma unroll
        for (int n = 0; n < 4; ++n) {
            const int rbase = wave * 32 + n * 8;
            async_copy16(qa + (size_t)rbase * ND + k0 + lsrc, &As[rbase * 64]);
            async_copy16(xa + (size_t)rbase * ND + k0 + lsrc, &Bs[rbase * 64]);
        }
        __builtin_amdgcn_s_waitcnt(0);
        __syncthreads();
        #pragma unroll
        for (int kc = 0; kc < 2; ++kc) {
            bf16x8 af[4], bfr[4];
            #pragma unroll
            for (int mi = 0; mi < 4; ++mi)
                af[mi] = *(const bf16x8*)&As[(wm * 64 + mi * 16 + l15) * 64 + (((kc * 4 + quad) ^ swz) << 3)];
            #pragma unroll
            for (int nj = 0; nj < 4; ++nj)
                bfr[nj] = *(const bf16x8*)&Bs[(wn * 64 + nj * 16 + l15) * 64 + (((kc * 4 + quad) ^ swz) << 3)];
            #pragma unroll
            for (int mi = 0; mi < 4; ++mi)
                #pragma unroll
                for (int nj = 0; nj < 4; ++nj)
                    acc[mi][nj] = __builtin_amdgcn_mfma_f32_16x16x32_bf16(af[mi], bfr[nj], acc[mi][nj], 0, 0, 0);
        }
        __syncthreads();
    }
    float gp[4][4] = {};
    #pragma unroll
    for (int nj = 0; nj < 4; ++nj) {
        const float wt = wlast[t0 + wn * 64 + nj * 16 + l15];
        #pragma unroll
        for (int mi = 0; mi < 4; ++mi)
            #pragma unroll
            for (int r = 0; r < 4; ++r) {
                const float e = __expf(-acc[mi][nj][r]);
                const float sg = __builtin_amdgcn_rcpf(1.f + e);
                gp[mi][r] = fmaf(sg, wt, gp[mi][r]);
            }
    }
    #pragma unroll
    for (int mi = 0; mi < 4; ++mi)
        #pragma unroll
        for (int r = 0; r < 4; ++r) {
            float v = gp[mi][r];
            v += __shfl_xor(v, 1);
            v += __shfl_xor(v, 2);
            v += __shfl_xor(v, 4);
            v += __shfl_xor(v, 8);
            if (l15 == 0) {
                const int srow = s0 + wm * 64 + mi * 16 + quad * 4 + r;
                if (srow < TM1) atomicAdd(&g0[b * TM1 + srow], v);
            }
        }
}

// --- r partials from bf16 xst (coalesced d-major) ------------------------
// r0acc[b,d] += sum_{s in chunk} xst[s][d]*g0[b,s]; sxacc += sum xst[s][d]
__global__ __launch_bounds__(256) void k_r(const ushort_t* __restrict__ xst,
                                           const float* __restrict__ g0,
                                           float* __restrict__ r0acc,
                                           float* __restrict__ sxacc, int b0) {
    const int sc = blockIdx.x;            // s-chunk of 256
    const int cc = blockIdx.y;
    const int b = b0 + cc;
    const ushort_t* xa = xst + (size_t)cc * BATCH_US;
    const float* g = g0 + b * TM1;
    const int d2 = threadIdx.x;           // owns d = 2*d2, 2*d2+1
    float a00 = 0.f, a01 = 0.f, a10 = 0.f, a11 = 0.f;
    const int send = (sc == 7) ? 255 : 256;   // exclude s = 2047
    for (int si = 0; si < send; ++si) {
        const int s = sc * 256 + si;
        const float gv = g[s];
        const uint_t pk = *(const uint_t*)&xa[(size_t)s * ND + d2 * 2];
        const float x0 = bf2f(pk & 0xFFFFu);
        const float x1 = bf2f(pk >> 16);
        a00 = fmaf(x0, gv, a00); a01 = fmaf(x1, gv, a01);
        a10 += x0; a11 += x1;
    }
    atomicAdd(&r0acc[b * ND + d2 * 2], a00);
    atomicAdd(&r0acc[b * ND + d2 * 2 + 1], a01);
    atomicAdd(&sxacc[b * ND + d2 * 2], a10);
    atomicAdd(&sxacc[b * ND + d2 * 2 + 1], a11);
}

// --- out[b,i] = sum_d W_PV[i,d] * r[b, i/256, d]  (fp32 out) -------------
__global__ __launch_bounds__(256) void k_out(const float* __restrict__ wpv,
                                             const float* __restrict__ r0acc,
                                             const float* __restrict__ sxacc,
                                             const float* __restrict__ wsum,
                                             float* __restrict__ out) {
    const int b = blockIdx.x;
    __shared__ float rs[1024];
    const float wsv = *wsum;
    for (int i = threadIdx.x; i < ND; i += 256) {
        const float r0 = r0acc[b * ND + i];
        const float sx = sxacc[b * ND + i];
        rs[i] = r0;                        // head 0
        rs[ND + i] = fmaf(wsv, sx, -r0);   // head 1
    }
    __syncthreads();
    for (int i = threadIdx.x; i < ND; i += 256) {
        const float* wrow = wpv + (size_t)i * ND;
        const float* rh = rs + (i >> 8) * ND;
        float acc = 0.f;
        for (int dd = 0; dd < ND; dd += 4) {
            const float4 wv = *(const float4*)(wrow + dd);
            acc += wv.x * rh[dd] + wv.y * rh[dd + 1] + wv.z * rh[dd + 2] + wv.w * rh[dd + 3];
        }
        out[b * ND + i] = acc;
    }
}

extern "C" void kernel_launch(void* const* d_in, const int* in_sizes, int n_in,
                              void* d_out, int out_size, void* d_ws, size_t ws_size,
                              hipStream_t stream) {
    (void)in_sizes; (void)n_in; (void)out_size;
    const float* xs   = (const float*)d_in[0];
    const float* wkq  = (const float*)d_in[1];
    const float* wpv  = (const float*)d_in[2];
    const float* wout = (const float*)d_in[3];
    const float* wlast = wout + (size_t)(NT - 1) * NT;  // W_out[-1]

    float* ws    = (float*)d_ws;
    float* g0    = ws + G0_OFF;
    float* r0acc = ws + R0_OFF;
    float* sxacc = ws + SX_OFF;
    float* wsum  = ws + WSUM_OFF;
    ushort_t* wkqT = (ushort_t*)(ws + WKQT_OFF);

    // Chunk batches: per batch needs 2 MB qdb + 2 MB xst of ws.
    const size_t ws_floats = ws_size / 4;
    size_t avail = (ws_floats > CHUNK_OFF) ? (ws_floats - CHUNK_OFF) : 0;
    int C = (int)(avail / BATCH_FLOATS);
    if (C > NB) C = NB;
    if (C < 1) C = 1;
    ushort_t* qdb = (ushort_t*)(ws + CHUNK_OFF);
    ushort_t* xst = (ushort_t*)(ws + CHUNK_OFF + (size_t)C * 524288ull);

    k_prep<<<dim3(16, 16), 256, 0, stream>>>(wkq, wkqT, wlast, wsum, ws);
    for (int b0 = 0; b0 < NB; b0 += C) {
        const int cb = (NB - b0 < C) ? (NB - b0) : C;
        k_cvt_xst<<<dim3(32, 8, cb), 256, 0, stream>>>(xs, xst, b0);
        k_qd     <<<dim3(4, 16, cb),  256, 0, stream>>>(xst, wkqT, qdb);
        k_attn   <<<dim3(16, 16, cb), 256, 0, stream>>>(qdb, xst, wlast, g0, b0);
        k_r      <<<dim3(8, cb),      256, 0, stream>>>(xst, g0, r0acc, sxacc, b0);
    }
    k_out<<<NB, 256, 0, stream>>>(wpv, r0acc, sxacc, wsum, (float*)d_out);
}

// Round 9
// 296.992 us; speedup vs baseline: 1.1587x; 1.1587x over previous
//
#include <hip/hip_runtime.h>
#include <hip/hip_bf16.h>

// Problem constants
#define NB 16
#define ND 512
#define NT 2048
#define TM1 2047
#define NHD 256

typedef __attribute__((ext_vector_type(8))) short bf16x8;
typedef __attribute__((ext_vector_type(4))) float f32x4;
typedef unsigned short ushort_t;
typedef unsigned int uint_t;

// ws layout (float offsets): zeroed head [0,49152), wsum, wkqT, chunk bufs.
#define G0_OFF    0ull
#define G0_ELEMS  (16ull * 2047ull)        // 32,752
#define R0_OFF    32768ull                 // r0acc [16][512]
#define SX_OFF    40960ull                 // sxacc [16][512]
#define ZERO_FLOATS 49152ull               // zeroed by k_prep
#define WSUM_OFF  49152ull
#define WKQT_OFF  49408ull                 // 512*512 bf16 = 131072 floats
#define CHUNK_OFF 180480ull
#define BATCH_US  (2048ull * 512ull)       // ushorts per batch per array (2 MB)
#define BATCH_FLOATS (2ull * 524288ull)    // qdb + xst floats per batch (4 MB)

__device__ __forceinline__ ushort_t f2bf(float x) {
    union { float f; uint_t u; } v; v.f = x;
    uint_t r = v.u + 0x7FFFu + ((v.u >> 16) & 1u);  // round-to-nearest-even
    return (ushort_t)(r >> 16);
}
__device__ __forceinline__ float bf2f(uint_t u) {
    union { uint_t u; float f; } v; v.u = u << 16;
    return v.f;
}

// Async global->LDS DMA, 16 B/lane, 1024 B/wave-instruction.
__device__ __forceinline__ void async_copy16(const ushort_t* g, ushort_t* l) {
    __builtin_amdgcn_global_load_lds(
        (const __attribute__((address_space(1))) void*)g,
        (__attribute__((address_space(3))) void*)l, 16, 0, 0);
}

// --- prep: wkqT = bf16(wkq^T);  zero g0/r0acc/sxacc;  wsum = sum(wlast) --
__global__ __launch_bounds__(256) void k_prep(const float* __restrict__ wkq,
                                              ushort_t* __restrict__ wkqT,
                                              const float* __restrict__ wlast,
                                              float* __restrict__ wsum,
                                              float* __restrict__ zbase) {
    __shared__ float tile[32][33];
    const int j0 = blockIdx.x * 32, d0 = blockIdx.y * 32;
    const int c = threadIdx.x & 31, r = threadIdx.x >> 5;  // r in 0..7
    #pragma unroll
    for (int i = 0; i < 4; ++i) {
        const int d = r + i * 8;
        tile[d][c] = wkq[(size_t)(d0 + d) * ND + j0 + c];
    }
    __syncthreads();
    #pragma unroll
    for (int i = 0; i < 4; ++i) {
        const int j = r + i * 8;
        wkqT[(size_t)(j0 + j) * ND + d0 + c] = f2bf(tile[c][j]);
    }
    // zero head scratch: 49152 floats over 256 blocks x 192 threads
    const int bid = blockIdx.y * 16 + blockIdx.x;
    if (threadIdx.x < 192) zbase[bid * 192 + threadIdx.x] = 0.f;
    // block 0 reduces wlast -> wsum
    if (bid == 0) {
        __shared__ float red[256];
        float s = 0.f;
        for (int t = threadIdx.x; t < NT; t += 256) s += wlast[t];
        red[threadIdx.x] = s;
        __syncthreads();
        for (int off = 128; off > 0; off >>= 1) {
            if (threadIdx.x < off) red[threadIdx.x] += red[threadIdx.x + off];
            __syncthreads();
        }
        if (threadIdx.x == 0) *wsum = red[0];
    }
}

// --- xst[c][t][d] = bf16(xs[b0+c][d][t]); 64x64 tiles, uint4 stores ------
__global__ __launch_bounds__(256) void k_cvt_xst(const float* __restrict__ xs,
                                                 ushort_t* __restrict__ xst, int b0) {
    __shared__ float tile[64][65];
    const int t0 = blockIdx.x * 64, d0 = blockIdx.y * 64;
    const int cc = blockIdx.z;
    const float* xb = xs + (size_t)(b0 + cc) * ND * NT;
    ushort_t* xo = xst + (size_t)cc * BATCH_US;
    {
        const int r = threadIdx.x >> 4;          // 0..15
        const int c4 = (threadIdx.x & 15) * 4;   // 0..60
        #pragma unroll
        for (int i = 0; i < 4; ++i) {
            const int d = r + i * 16;
            *(float4*)&tile[d][c4] = *(const float4*)&xb[(size_t)(d0 + d) * NT + t0 + c4];
        }
    }
    __syncthreads();
    {
        const int row = threadIdx.x >> 3;        // 0..31
        const int c8 = (threadIdx.x & 7) * 8;    // 0..56
        #pragma unroll
        for (int i = 0; i < 2; ++i) {
            const int t = row + i * 32;
            uint_t w[4];
            #pragma unroll
            for (int p = 0; p < 4; ++p)
                w[p] = (uint_t)f2bf(tile[c8 + 2 * p][t]) |
                       ((uint_t)f2bf(tile[c8 + 2 * p + 1][t]) << 16);
            *(uint4*)&xo[(size_t)(t0 + t) * ND + d0 + c8] = *(uint4*)w;
        }
    }
}

// --- qdb[c][s][j] = bf16( sign_j * sum_d xst[c][s][d] * wkqT[j][d] ) -----
__global__ __launch_bounds__(256) void k_qd(const ushort_t* __restrict__ xst,
                                            const ushort_t* __restrict__ wkqT,
                                            ushort_t* __restrict__ qdb) {
    const int j0 = blockIdx.x * 128;
    const int s0 = blockIdx.y * 128;
    const int cc = blockIdx.z;
    __shared__ __align__(16) ushort_t As[128 * 64];
    __shared__ __align__(16) ushort_t Bs[128 * 64];
    const int tid = threadIdx.x;
    const int wave = tid >> 6, lane = tid & 63;
    const int l15 = lane & 15, quad = lane >> 4;
    const int wm = wave >> 1, wn = wave & 1;
    const int swz = l15 & 7;
    const int lrow = lane >> 3;
    const size_t lsrc = (size_t)lrow * ND + (size_t)(((lane & 7) ^ lrow) << 3);
    const ushort_t* xa = xst + (size_t)cc * BATCH_US + (size_t)s0 * ND;
    const ushort_t* wb = wkqT + (size_t)j0 * ND;
    ushort_t* qo = qdb + (size_t)cc * BATCH_US;
    f32x4 acc[4][4];
    #pragma unroll
    for (int mi = 0; mi < 4; ++mi)
        #pragma unroll
        for (int nj = 0; nj < 4; ++nj) acc[mi][nj] = (f32x4){0.f, 0.f, 0.f, 0.f};
    for (int ks = 0; ks < 8; ++ks) {
        const int k0 = ks * 64;
        #pragma unroll
        for (int n = 0; n < 4; ++n) {
            const int rbase = wave * 32 + n * 8;
            async_copy16(xa + (size_t)rbase * ND + k0 + lsrc, &As[rbase * 64]);
            async_copy16(wb + (size_t)rbase * ND + k0 + lsrc, &Bs[rbase * 64]);
        }
        __builtin_amdgcn_s_waitcnt(0);
        __syncthreads();
        #pragma unroll
        for (int kc = 0; kc < 2; ++kc) {
            bf16x8 af[4], bfr[4];
            #pragma unroll
            for (int mi = 0; mi < 4; ++mi)
                af[mi] = *(const bf16x8*)&As[(wm * 64 + mi * 16 + l15) * 64 + (((kc * 4 + quad) ^ swz) << 3)];
            #pragma unroll
            for (int nj = 0; nj < 4; ++nj)
                bfr[nj] = *(const bf16x8*)&Bs[(wn * 64 + nj * 16 + l15) * 64 + (((kc * 4 + quad) ^ swz) << 3)];
            #pragma unroll
            for (int mi = 0; mi < 4; ++mi)
                #pragma unroll
                for (int nj = 0; nj < 4; ++nj)
                    acc[mi][nj] = __builtin_amdgcn_mfma_f32_16x16x32_bf16(af[mi], bfr[nj], acc[mi][nj], 0, 0, 0);
        }
        __syncthreads();
    }
    #pragma unroll
    for (int mi = 0; mi < 4; ++mi) {
        const int srow = s0 + wm * 64 + mi * 16 + quad * 4;
        #pragma unroll
        for (int nj = 0; nj < 4; ++nj) {
            const int jcol = j0 + wn * 64 + nj * 16 + l15;
            const float sgn = (jcol < NHD) ? 1.f : -1.f;
            #pragma unroll
            for (int r = 0; r < 4; ++r)
                qo[(size_t)(srow + r) * ND + jcol] = f2bf(sgn * acc[mi][nj][r]);
        }
    }
}

// --- g0[b,s] += sum_t sigmoid(Delta[b,s,t]) * w[t] -----------------------
__global__ __launch_bounds__(256) void k_attn(const ushort_t* __restrict__ qdb,
                                              const ushort_t* __restrict__ xst,
                                              const float* __restrict__ wlast,
                                              float* __restrict__ g0, int b0) {
    const int t0 = blockIdx.x * 128;
    const int s0 = blockIdx.y * 128;
    const int cc = blockIdx.z;
    const int b = b0 + cc;
    __shared__ __align__(16) ushort_t As[128 * 64];
    __shared__ __align__(16) ushort_t Bs[128 * 64];
    const int tid = threadIdx.x;
    const int wave = tid >> 6, lane = tid & 63;
    const int l15 = lane & 15, quad = lane >> 4;
    const int wm = wave >> 1, wn = wave & 1;
    const int swz = l15 & 7;
    const int lrow = lane >> 3;
    const size_t lsrc = (size_t)lrow * ND + (size_t)(((lane & 7) ^ lrow) << 3);
    const ushort_t* qa = qdb + (size_t)cc * BATCH_US + (size_t)s0 * ND;
    const ushort_t* xa = xst + (size_t)cc * BATCH_US + (size_t)t0 * ND;
    f32x4 acc[4][4];
    #pragma unroll
    for (int mi = 0; mi < 4; ++mi)
        #pragma unroll
        for (int nj = 0; nj < 4; ++nj) acc[mi][nj] = (f32x4){0.f, 0.f, 0.f, 0.f};
    for (int ks = 0; ks < 8; ++ks) {
        const int k0 = ks * 64;
        #pragma unroll
        for (int n = 0; n < 4; ++n) {
            const int rbase = wave * 32 + n * 8;
            async_copy16(qa + (size_t)rbase * ND + k0 + lsrc, &As[rbase * 64]);
            async_copy16(xa + (size_t)rbase * ND + k0 + lsrc, &Bs[rbase * 64]);
        }
        __builtin_amdgcn_s_waitcnt(0);
        __syncthreads();
        #pragma unroll
        for (int kc = 0; kc < 2; ++kc) {
            bf16x8 af[4], bfr[4];
            #pragma unroll
            for (int mi = 0; mi < 4; ++mi)
                af[mi] = *(const bf16x8*)&As[(wm * 64 + mi * 16 + l15) * 64 + (((kc * 4 + quad) ^ swz) << 3)];
            #pragma unroll
            for (int nj = 0; nj < 4; ++nj)
                bfr[nj] = *(const bf16x8*)&Bs[(wn * 64 + nj * 16 + l15) * 64 + (((kc * 4 + quad) ^ swz) << 3)];
            #pragma unroll
            for (int mi = 0; mi < 4; ++mi)
                #pragma unroll
                for (int nj = 0; nj < 4; ++nj)
                    acc[mi][nj] = __builtin_amdgcn_mfma_f32_16x16x32_bf16(af[mi], bfr[nj], acc[mi][nj], 0, 0, 0);
        }
        __syncthreads();
    }
    float gp[4][4] = {};
    #pragma unroll
    for (int nj = 0; nj < 4; ++nj) {
        const float wt = wlast[t0 + wn * 64 + nj * 16 + l15];
        #pragma unroll
        for (int mi = 0; mi < 4; ++mi)
            #pragma unroll
            for (int r = 0; r < 4; ++r) {
                const float e = __expf(-acc[mi][nj][r]);
                const float sg = __builtin_amdgcn_rcpf(1.f + e);
                gp[mi][r] = fmaf(sg, wt, gp[mi][r]);
            }
    }
    #pragma unroll
    for (int mi = 0; mi < 4; ++mi)
        #pragma unroll
        for (int r = 0; r < 4; ++r) {
            float v = gp[mi][r];
            v += __shfl_xor(v, 1);
            v += __shfl_xor(v, 2);
            v += __shfl_xor(v, 4);
            v += __shfl_xor(v, 8);
            if (l15 == 0) {
                const int srow = s0 + wm * 64 + mi * 16 + quad * 4 + r;
                if (srow < TM1) atomicAdd(&g0[b * TM1 + srow], v);
            }
        }
}

// --- r partials from bf16 xst (coalesced d-major) ------------------------
// r0acc[b,d] += sum_{s in chunk} xst[s][d]*g0[b,s]; sxacc += sum xst[s][d]
// Grid (32, cb): 64 s per block -> 512 blocks per full pass (2 blocks/CU).
__global__ __launch_bounds__(256) void k_r(const ushort_t* __restrict__ xst,
                                           const float* __restrict__ g0,
                                           float* __restrict__ r0acc,
                                           float* __restrict__ sxacc, int b0) {
    const int sc = blockIdx.x;            // s-chunk of 64
    const int cc = blockIdx.y;
    const int b = b0 + cc;
    const ushort_t* xa = xst + (size_t)cc * BATCH_US;
    const float* g = g0 + b * TM1;
    const int d2 = threadIdx.x;           // owns d = 2*d2, 2*d2+1
    float a00 = 0.f, a01 = 0.f, a10 = 0.f, a11 = 0.f;
    const int send = (sc == 31) ? 63 : 64;   // exclude s = 2047
    for (int si = 0; si < send; ++si) {
        const int s = sc * 64 + si;
        const float gv = g[s];
        const uint_t pk = *(const uint_t*)&xa[(size_t)s * ND + d2 * 2];
        const float x0 = bf2f(pk & 0xFFFFu);
        const float x1 = bf2f(pk >> 16);
        a00 = fmaf(x0, gv, a00); a01 = fmaf(x1, gv, a01);
        a10 += x0; a11 += x1;
    }
    atomicAdd(&r0acc[b * ND + d2 * 2], a00);
    atomicAdd(&r0acc[b * ND + d2 * 2 + 1], a01);
    atomicAdd(&sxacc[b * ND + d2 * 2], a10);
    atomicAdd(&sxacc[b * ND + d2 * 2 + 1], a11);
}

// --- out[b,i] = sum_d W_PV[i,d] * r[b, i/256, d]  (fp32 out) -------------
__global__ __launch_bounds__(256) void k_out(const float* __restrict__ wpv,
                                             const float* __restrict__ r0acc,
                                             const float* __restrict__ sxacc,
                                             const float* __restrict__ wsum,
                                             float* __restrict__ out) {
    const int b = blockIdx.x;
    const int i0 = blockIdx.y * 256;
    __shared__ float rs[1024];
    const float wsv = *wsum;
    for (int i = threadIdx.x; i < ND; i += 256) {
        const float r0 = r0acc[b * ND + i];
        const float sx = sxacc[b * ND + i];
        rs[i] = r0;                        // head 0
        rs[ND + i] = fmaf(wsv, sx, -r0);   // head 1
    }
    __syncthreads();
    const int i = i0 + threadIdx.x;
    const float* wrow = wpv + (size_t)i * ND;
    const float* rh = rs + (i >> 8) * ND;
    float acc = 0.f;
    for (int dd = 0; dd < ND; dd += 4) {
        const float4 wv = *(const float4*)(wrow + dd);
        acc += wv.x * rh[dd] + wv.y * rh[dd + 1] + wv.z * rh[dd + 2] + wv.w * rh[dd + 3];
    }
    out[b * ND + i] = acc;
}

extern "C" void kernel_launch(void* const* d_in, const int* in_sizes, int n_in,
                              void* d_out, int out_size, void* d_ws, size_t ws_size,
                              hipStream_t stream) {
    (void)in_sizes; (void)n_in; (void)out_size;
    const float* xs   = (const float*)d_in[0];
    const float* wkq  = (const float*)d_in[1];
    const float* wpv  = (const float*)d_in[2];
    const float* wout = (const float*)d_in[3];
    const float* wlast = wout + (size_t)(NT - 1) * NT;  // W_out[-1]

    float* ws    = (float*)d_ws;
    float* g0    = ws + G0_OFF;
    float* r0acc = ws + R0_OFF;
    float* sxacc = ws + SX_OFF;
    float* wsum  = ws + WSUM_OFF;
    ushort_t* wkqT = (ushort_t*)(ws + WKQT_OFF);

    // Chunk batches: per batch needs 2 MB qdb + 2 MB xst of ws.
    const size_t ws_floats = ws_size / 4;
    size_t avail = (ws_floats > CHUNK_OFF) ? (ws_floats - CHUNK_OFF) : 0;
    int C = (int)(avail / BATCH_FLOATS);
    if (C > NB) C = NB;
    if (C < 1) C = 1;
    ushort_t* qdb = (ushort_t*)(ws + CHUNK_OFF);
    ushort_t* xst = (ushort_t*)(ws + CHUNK_OFF + (size_t)C * 524288ull);

    k_prep<<<dim3(16, 16), 256, 0, stream>>>(wkq, wkqT, wlast, wsum, ws);
    for (int b0 = 0; b0 < NB; b0 += C) {
        const int cb = (NB - b0 < C) ? (NB - b0) : C;
        k_cvt_xst<<<dim3(32, 8, cb), 256, 0, stream>>>(xs, xst, b0);
        k_qd     <<<dim3(4, 16, cb),  256, 0, stream>>>(xst, wkqT, qdb);
        k_attn   <<<dim3(16, 16, cb), 256, 0, stream>>>(qdb, xst, wlast, g0, b0);
        k_r      <<<dim3(32, cb),     256, 0, stream>>>(xst, g0, r0acc, sxacc, b0);
    }
    k_out<<<dim3(NB, 2), 256, 0, stream>>>(wpv, r0acc, sxacc, wsum, (float*)d_out);
}

// Round 10
// 290.350 us; speedup vs baseline: 1.1852x; 1.0229x over previous
//
#include <hip/hip_runtime.h>
#include <hip/hip_bf16.h>

// Problem constants
#define NB 16
#define ND 512
#define NT 2048
#define TM1 2047
#define NHD 256

typedef __attribute__((ext_vector_type(8))) short bf16x8;
typedef __attribute__((ext_vector_type(4))) float f32x4;
typedef unsigned short ushort_t;
typedef unsigned int uint_t;

// ws layout (float offsets): zeroed head [0,49152), wsum, wkqT, chunk bufs.
#define G0_OFF    0ull
#define G0_ELEMS  (16ull * 2047ull)        // 32,752
#define R0_OFF    32768ull                 // r0acc [16][512]
#define SX_OFF    40960ull                 // sxacc [16][512]
#define ZERO_FLOATS 49152ull               // zeroed by k_prep
#define WSUM_OFF  49152ull
#define WKQT_OFF  49408ull                 // 512*512 bf16 = 131072 floats
#define CHUNK_OFF 180480ull
#define BATCH_US  (2048ull * 512ull)       // ushorts per batch per array (2 MB)
#define BATCH_FLOATS (2ull * 524288ull)    // qdb + xst floats per batch (4 MB)

__device__ __forceinline__ ushort_t f2bf(float x) {
    union { float f; uint_t u; } v; v.f = x;
    uint_t r = v.u + 0x7FFFu + ((v.u >> 16) & 1u);  // round-to-nearest-even
    return (ushort_t)(r >> 16);
}
__device__ __forceinline__ float bf2f(uint_t u) {
    union { uint_t u; float f; } v; v.u = u << 16;
    return v.f;
}

// Async global->LDS DMA, 16 B/lane, 1024 B/wave-instruction.
__device__ __forceinline__ void async_copy16(const ushort_t* g, ushort_t* l) {
    __builtin_amdgcn_global_load_lds(
        (const __attribute__((address_space(1))) void*)g,
        (__attribute__((address_space(3))) void*)l, 16, 0, 0);
}

// --- prep: wkqT = bf16(wkq^T);  zero g0/r0acc/sxacc;  wsum = sum(wlast) --
__global__ __launch_bounds__(256) void k_prep(const float* __restrict__ wkq,
                                              ushort_t* __restrict__ wkqT,
                                              const float* __restrict__ wlast,
                                              float* __restrict__ wsum,
                                              float* __restrict__ zbase) {
    __shared__ float tile[32][33];
    const int j0 = blockIdx.x * 32, d0 = blockIdx.y * 32;
    const int c = threadIdx.x & 31, r = threadIdx.x >> 5;  // r in 0..7
    #pragma unroll
    for (int i = 0; i < 4; ++i) {
        const int d = r + i * 8;
        tile[d][c] = wkq[(size_t)(d0 + d) * ND + j0 + c];
    }
    __syncthreads();
    #pragma unroll
    for (int i = 0; i < 4; ++i) {
        const int j = r + i * 8;
        wkqT[(size_t)(j0 + j) * ND + d0 + c] = f2bf(tile[c][j]);
    }
    // zero head scratch: 49152 floats over 256 blocks x 192 threads
    const int bid = blockIdx.y * 16 + blockIdx.x;
    if (threadIdx.x < 192) zbase[bid * 192 + threadIdx.x] = 0.f;
    // block 0 reduces wlast -> wsum
    if (bid == 0) {
        __shared__ float red[256];
        float s = 0.f;
        for (int t = threadIdx.x; t < NT; t += 256) s += wlast[t];
        red[threadIdx.x] = s;
        __syncthreads();
        for (int off = 128; off > 0; off >>= 1) {
            if (threadIdx.x < off) red[threadIdx.x] += red[threadIdx.x + off];
            __syncthreads();
        }
        if (threadIdx.x == 0) *wsum = red[0];
    }
}

// --- xst[c][t][d] = bf16(xs[b0+c][d][t]) ---------------------------------
// 256t x 64d tiles: reads are full-wave 1024 B contiguous per d-row.
__global__ __launch_bounds__(256) void k_cvt_xst(const float* __restrict__ xs,
                                                 ushort_t* __restrict__ xst, int b0) {
    __shared__ float tile[64][257];
    const int t0 = blockIdx.x * 256, d0 = blockIdx.y * 64;
    const int cc = blockIdx.z;
    const float* xb = xs + (size_t)(b0 + cc) * ND * NT;
    ushort_t* xo = xst + (size_t)cc * BATCH_US;
    const int wave = threadIdx.x >> 6, lane = threadIdx.x & 63;
    // read: 64 d-rows, each 256 floats = 64 lanes x float4 (1024 B contiguous)
    #pragma unroll
    for (int i = 0; i < 16; ++i) {
        const int row = wave * 16 + i;
        *(float4*)&tile[row][lane * 4] =
            *(const float4*)&xb[(size_t)(d0 + row) * NT + t0 + lane * 4];
    }
    __syncthreads();
    // write: 256 t-rows, each 64 bf16 = 8 lanes x uint4 (128 B contiguous)
    const int c8 = (threadIdx.x & 7) * 8;
    #pragma unroll
    for (int i = 0; i < 8; ++i) {
        const int t = i * 32 + (threadIdx.x >> 3);
        uint_t w[4];
        #pragma unroll
        for (int p = 0; p < 4; ++p)
            w[p] = (uint_t)f2bf(tile[c8 + 2 * p][t]) |
                   ((uint_t)f2bf(tile[c8 + 2 * p + 1][t]) << 16);
        *(uint4*)&xo[(size_t)(t0 + t) * ND + d0 + c8] = *(uint4*)w;
    }
}

// --- qdb[c][s][j] = bf16( sign_j * sum_d xst[c][s][d] * wkqT[j][d] ) -----
__global__ __launch_bounds__(256) void k_qd(const ushort_t* __restrict__ xst,
                                            const ushort_t* __restrict__ wkqT,
                                            ushort_t* __restrict__ qdb) {
    const int j0 = blockIdx.x * 128;
    const int s0 = blockIdx.y * 128;
    const int cc = blockIdx.z;
    __shared__ __align__(16) ushort_t As[128 * 64];
    __shared__ __align__(16) ushort_t Bs[128 * 64];
    const int tid = threadIdx.x;
    const int wave = tid >> 6, lane = tid & 63;
    const int l15 = lane & 15, quad = lane >> 4;
    const int wm = wave >> 1, wn = wave & 1;
    const int swz = l15 & 7;
    const int lrow = lane >> 3;
    const size_t lsrc = (size_t)lrow * ND + (size_t)(((lane & 7) ^ lrow) << 3);
    const ushort_t* xa = xst + (size_t)cc * BATCH_US + (size_t)s0 * ND;
    const ushort_t* wb = wkqT + (size_t)j0 * ND;
    ushort_t* qo = qdb + (size_t)cc * BATCH_US;
    f32x4 acc[4][4];
    #pragma unroll
    for (int mi = 0; mi < 4; ++mi)
        #pragma unroll
        for (int nj = 0; nj < 4; ++nj) acc[mi][nj] = (f32x4){0.f, 0.f, 0.f, 0.f};
    for (int ks = 0; ks < 8; ++ks) {
        const int k0 = ks * 64;
        #pragma unroll
        for (int n = 0; n < 4; ++n) {
            const int rbase = wave * 32 + n * 8;
            async_copy16(xa + (size_t)rbase * ND + k0 + lsrc, &As[rbase * 64]);
            async_copy16(wb + (size_t)rbase * ND + k0 + lsrc, &Bs[rbase * 64]);
        }
        __builtin_amdgcn_s_waitcnt(0);
        __syncthreads();
        #pragma unroll
        for (int kc = 0; kc < 2; ++kc) {
            bf16x8 af[4], bfr[4];
            #pragma unroll
            for (int mi = 0; mi < 4; ++mi)
                af[mi] = *(const bf16x8*)&As[(wm * 64 + mi * 16 + l15) * 64 + (((kc * 4 + quad) ^ swz) << 3)];
            #pragma unroll
            for (int nj = 0; nj < 4; ++nj)
                bfr[nj] = *(const bf16x8*)&Bs[(wn * 64 + nj * 16 + l15) * 64 + (((kc * 4 + quad) ^ swz) << 3)];
            #pragma unroll
            for (int mi = 0; mi < 4; ++mi)
                #pragma unroll
                for (int nj = 0; nj < 4; ++nj)
                    acc[mi][nj] = __builtin_amdgcn_mfma_f32_16x16x32_bf16(af[mi], bfr[nj], acc[mi][nj], 0, 0, 0);
        }
        __syncthreads();
    }
    #pragma unroll
    for (int mi = 0; mi < 4; ++mi) {
        const int srow = s0 + wm * 64 + mi * 16 + quad * 4;
        #pragma unroll
        for (int nj = 0; nj < 4; ++nj) {
            const int jcol = j0 + wn * 64 + nj * 16 + l15;
            const float sgn = (jcol < NHD) ? 1.f : -1.f;
            #pragma unroll
            for (int r = 0; r < 4; ++r)
                qo[(size_t)(srow + r) * ND + jcol] = f2bf(sgn * acc[mi][nj][r]);
        }
    }
}

// --- g0[b,s] += sum_t sigmoid(Delta[b,s,t]) * w[t] -----------------------
__global__ __launch_bounds__(256) void k_attn(const ushort_t* __restrict__ qdb,
                                              const ushort_t* __restrict__ xst,
                                              const float* __restrict__ wlast,
                                              float* __restrict__ g0, int b0) {
    const int t0 = blockIdx.x * 128;
    const int s0 = blockIdx.y * 128;
    const int cc = blockIdx.z;
    const int b = b0 + cc;
    __shared__ __align__(16) ushort_t As[128 * 64];
    __shared__ __align__(16) ushort_t Bs[128 * 64];
    const int tid = threadIdx.x;
    const int wave = tid >> 6, lane = tid & 63;
    const int l15 = lane & 15, quad = lane >> 4;
    const int wm = wave >> 1, wn = wave & 1;
    const int swz = l15 & 7;
    const int lrow = lane >> 3;
    const size_t lsrc = (size_t)lrow * ND + (size_t)(((lane & 7) ^ lrow) << 3);
    const ushort_t* qa = qdb + (size_t)cc * BATCH_US + (size_t)s0 * ND;
    const ushort_t* xa = xst + (size_t)cc * BATCH_US + (size_t)t0 * ND;
    f32x4 acc[4][4];
    #pragma unroll
    for (int mi = 0; mi < 4; ++mi)
        #pragma unroll
        for (int nj = 0; nj < 4; ++nj) acc[mi][nj] = (f32x4){0.f, 0.f, 0.f, 0.f};
    for (int ks = 0; ks < 8; ++ks) {
        const int k0 = ks * 64;
        #pragma unroll
        for (int n = 0; n < 4; ++n) {
            const int rbase = wave * 32 + n * 8;
            async_copy16(qa + (size_t)rbase * ND + k0 + lsrc, &As[rbase * 64]);
            async_copy16(xa + (size_t)rbase * ND + k0 + lsrc, &Bs[rbase * 64]);
        }
        __builtin_amdgcn_s_waitcnt(0);
        __syncthreads();
        #pragma unroll
        for (int kc = 0; kc < 2; ++kc) {
            bf16x8 af[4], bfr[4];
            #pragma unroll
            for (int mi = 0; mi < 4; ++mi)
                af[mi] = *(const bf16x8*)&As[(wm * 64 + mi * 16 + l15) * 64 + (((kc * 4 + quad) ^ swz) << 3)];
            #pragma unroll
            for (int nj = 0; nj < 4; ++nj)
                bfr[nj] = *(const bf16x8*)&Bs[(wn * 64 + nj * 16 + l15) * 64 + (((kc * 4 + quad) ^ swz) << 3)];
            #pragma unroll
            for (int mi = 0; mi < 4; ++mi)
                #pragma unroll
                for (int nj = 0; nj < 4; ++nj)
                    acc[mi][nj] = __builtin_amdgcn_mfma_f32_16x16x32_bf16(af[mi], bfr[nj], acc[mi][nj], 0, 0, 0);
        }
        __syncthreads();
    }
    float gp[4][4] = {};
    #pragma unroll
    for (int nj = 0; nj < 4; ++nj) {
        const float wt = wlast[t0 + wn * 64 + nj * 16 + l15];
        #pragma unroll
        for (int mi = 0; mi < 4; ++mi)
            #pragma unroll
            for (int r = 0; r < 4; ++r) {
                const float e = __expf(-acc[mi][nj][r]);
                const float sg = __builtin_amdgcn_rcpf(1.f + e);
                gp[mi][r] = fmaf(sg, wt, gp[mi][r]);
            }
    }
    #pragma unroll
    for (int mi = 0; mi < 4; ++mi)
        #pragma unroll
        for (int r = 0; r < 4; ++r) {
            float v = gp[mi][r];
            v += __shfl_xor(v, 1);
            v += __shfl_xor(v, 2);
            v += __shfl_xor(v, 4);
            v += __shfl_xor(v, 8);
            if (l15 == 0) {
                const int srow = s0 + wm * 64 + mi * 16 + quad * 4 + r;
                if (srow < TM1) atomicAdd(&g0[b * TM1 + srow], v);
            }
        }
}

// --- r partials from bf16 xst (coalesced d-major) ------------------------
__global__ __launch_bounds__(256) void k_r(const ushort_t* __restrict__ xst,
                                           const float* __restrict__ g0,
                                           float* __restrict__ r0acc,
                                           float* __restrict__ sxacc, int b0) {
    const int sc = blockIdx.x;            // s-chunk of 64
    const int cc = blockIdx.y;
    const int b = b0 + cc;
    const ushort_t* xa = xst + (size_t)cc * BATCH_US;
    const float* g = g0 + b * TM1;
    const int d2 = threadIdx.x;           // owns d = 2*d2, 2*d2+1
    float a00 = 0.f, a01 = 0.f, a10 = 0.f, a11 = 0.f;
    const int send = (sc == 31) ? 63 : 64;   // exclude s = 2047
    for (int si = 0; si < send; ++si) {
        const int s = sc * 64 + si;
        const float gv = g[s];
        const uint_t pk = *(const uint_t*)&xa[(size_t)s * ND + d2 * 2];
        const float x0 = bf2f(pk & 0xFFFFu);
        const float x1 = bf2f(pk >> 16);
        a00 = fmaf(x0, gv, a00); a01 = fmaf(x1, gv, a01);
        a10 += x0; a11 += x1;
    }
    atomicAdd(&r0acc[b * ND + d2 * 2], a00);
    atomicAdd(&r0acc[b * ND + d2 * 2 + 1], a01);
    atomicAdd(&sxacc[b * ND + d2 * 2], a10);
    atomicAdd(&sxacc[b * ND + d2 * 2 + 1], a11);
}

// --- out[b,i] = sum_d W_PV[i,d] * r[b, i/256, d]  (fp32 out) -------------
__global__ __launch_bounds__(256) void k_out(const float* __restrict__ wpv,
                                             const float* __restrict__ r0acc,
                                             const float* __restrict__ sxacc,
                                             const float* __restrict__ wsum,
                                             float* __restrict__ out) {
    const int b = blockIdx.x;
    const int i0 = blockIdx.y * 256;
    __shared__ float rs[1024];
    const float wsv = *wsum;
    for (int i = threadIdx.x; i < ND; i += 256) {
        const float r0 = r0acc[b * ND + i];
        const float sx = sxacc[b * ND + i];
        rs[i] = r0;                        // head 0
        rs[ND + i] = fmaf(wsv, sx, -r0);   // head 1
    }
    __syncthreads();
    const int i = i0 + threadIdx.x;
    const float* wrow = wpv + (size_t)i * ND;
    const float* rh = rs + (i >> 8) * ND;
    float acc = 0.f;
    for (int dd = 0; dd < ND; dd += 4) {
        const float4 wv = *(const float4*)(wrow + dd);
        acc += wv.x * rh[dd] + wv.y * rh[dd + 1] + wv.z * rh[dd + 2] + wv.w * rh[dd + 3];
    }
    out[b * ND + i] = acc;
}

extern "C" void kernel_launch(void* const* d_in, const int* in_sizes, int n_in,
                              void* d_out, int out_size, void* d_ws, size_t ws_size,
                              hipStream_t stream) {
    (void)in_sizes; (void)n_in; (void)out_size;
    const float* xs   = (const float*)d_in[0];
    const float* wkq  = (const float*)d_in[1];
    const float* wpv  = (const float*)d_in[2];
    const float* wout = (const float*)d_in[3];
    const float* wlast = wout + (size_t)(NT - 1) * NT;  // W_out[-1]

    float* ws    = (float*)d_ws;
    float* g0    = ws + G0_OFF;
    float* r0acc = ws + R0_OFF;
    float* sxacc = ws + SX_OFF;
    float* wsum  = ws + WSUM_OFF;
    ushort_t* wkqT = (ushort_t*)(ws + WKQT_OFF);

    // Chunk batches: per batch needs 2 MB qdb + 2 MB xst of ws.
    const size_t ws_floats = ws_size / 4;
    size_t avail = (ws_floats > CHUNK_OFF) ? (ws_floats - CHUNK_OFF) : 0;
    int C = (int)(avail / BATCH_FLOATS);
    if (C > NB) C = NB;
    if (C < 1) C = 1;
    ushort_t* qdb = (ushort_t*)(ws + CHUNK_OFF);
    ushort_t* xst = (ushort_t*)(ws + CHUNK_OFF + (size_t)C * 524288ull);

    k_prep<<<dim3(16, 16), 256, 0, stream>>>(wkq, wkqT, wlast, wsum, ws);
    for (int b0 = 0; b0 < NB; b0 += C) {
        const int cb = (NB - b0 < C) ? (NB - b0) : C;
        k_cvt_xst<<<dim3(8, 8, cb), 256, 0, stream>>>(xs, xst, b0);
        k_qd     <<<dim3(4, 16, cb),  256, 0, stream>>>(xst, wkqT, qdb);
        k_attn   <<<dim3(16, 16, cb), 256, 0, stream>>>(qdb, xst, wlast, g0, b0);
        k_r      <<<dim3(32, cb),     256, 0, stream>>>(xst, g0, r0acc, sxacc, b0);
    }
    k_out<<<dim3(NB, 2), 256, 0, stream>>>(wpv, r0acc, sxacc, wsum, (float*)d_out);
}